// Round 12
// baseline (67.354 us; speedup 1.0000x reference)
//
#include <hip/hip_runtime.h>
#include <cmath>

// GRNN_3547642986522 — B=4096 filters, T=2048 steps. SINGLE FUSED KERNEL (R12).
// Math: cov (Riccati) evolves by a CONSTANT LFT per step (Euler == Kalman LFT
// to O(dt^2)); host computes ML = M_step^16 and MH = M_step^1024 in double.
// x is affine given cov; f linear; t closed-form.
// Mapping: 2 waves per batch, lane = segment. NSEG=128 segments x 16 steps.
// wave w of batch owns segments [64w, 64w+64): per-lane checkpoint via binary
// matpow of ML (6-bit exponent) + one wave-uniform MH multiply for w=1.
// Phase 1: per-segment affine map (X,Q). Wave-local shfl_up scan (6 rounds);
// wave0's total map crosses to wave1 via 6 floats of LDS + one barrier.
// Phase 2: replay 16 steps emitting dy_hat. Segment-127 lane writes tails.
// Memory: wave covers one contiguous 8KB half-row; block = 2 batches (32KB),
// XCD-swizzled. dy read once (v[8] in registers), dy_hat written once.
// 8192 waves = 32/CU capacity (vs 16 in R11) -> 2x TLP for latency hiding.

#define NBATCH 4096
#define NT     2048
#define ROWF4  1024        // float4 per dy row

struct M16 { float m[16]; };

namespace gk {

constexpr float DT   = 0.001f;
constexpr float A00  = -0.15f;
constexpr float A01  = 6.283185f;
constexpr float A10  = -6.283185f;
constexpr float A11  = -0.15f;
constexpr float C0   = 1.6970562748477141f;
constexpr float DD   = 5.25f;

constexpr float P00c = 1.0f + DT*A00;
constexpr float P01c = DT*A01;
constexpr float P10c = DT*A10;
constexpr float P11c = 1.0f + DT*A11;
constexpr float DTC  = DT*C0;
constexpr float QQ   = DT*C0*C0;
constexpr float cVA  = 1.0f + 2.0f*DT*A00;
constexpr float cVB  = 2.0f*DT*A01;
constexpr float cVBn = 2.0f*DT*A10;
constexpr float cVD  = DT*DD;
constexpr float cCA  = 1.0f + DT*(A00+A11);
constexpr float cCB  = DT*A10;
constexpr float cCC  = DT*A01;
constexpr float YC   = C0*DT;

__device__ __forceinline__ void cov_step(float& vx, float& vp, float& cxp)
{
    float a1 = fmaf(-QQ, vx,  cVA);
    float b1 = fmaf(cVB, cxp, cVD);
    float a2 = fmaf(-QQ, cxp, cVBn);
    float b2 = fmaf(a2,  cxp, cVD);
    float a3 = fmaf(-QQ, vx,  cCA);
    float m  = cCC * vp;
    float c3 = fmaf(cCB, vx,  m);
    float nvx = fmaf(a1,  vx,  b1);
    float nvp = fmaf(cVA, vp,  b2);
    float ncx = fmaf(a3,  cxp, c3);
    vx = nvx; vp = nvp; cxp = ncx;
}

__device__ __forceinline__ void covf_step(
    float& vx, float& vp, float& cxp, float& f0, float& f1,
    float k00, float k01, float k10, float k11,
    float& xi0o, float& xi1o, float& nf0o)
{
    float xi0 = C0*vx, xi1 = C0*cxp;
    float nf0 = fmaf(DT, fmaf(k00, f0, k01*f1), f0);
    float nf1 = fmaf(DT, fmaf(k10, f0, k11*f1), f1);
    xi0o = xi0; xi1o = xi1; nf0o = nf0;
    cov_step(vx, vp, cxp);
    f0 = nf0; f1 = nf1;
}

__device__ __forceinline__ void mat4_mul(const float* A, const float* B, float* C)
{
    #pragma unroll
    for (int i = 0; i < 4; ++i)
        #pragma unroll
        for (int j = 0; j < 4; ++j) {
            float acc = A[i*4+0] * B[0*4+j];
            acc = fmaf(A[i*4+1], B[1*4+j], acc);
            acc = fmaf(A[i*4+2], B[2*4+j], acc);
            acc = fmaf(A[i*4+3], B[3*4+j], acc);
            C[i*4+j] = acc;
        }
}

// P -> (E P + F)(G P + H)^-1, P = [[vx,cxp],[cxp,vp]].
__device__ __forceinline__ void lft_apply(const float* m, float& vx, float& vp, float& cxp)
{
    float n00 = fmaf(m[0], vx,  fmaf(m[1], cxp, m[2]));
    float n01 = fmaf(m[0], cxp, fmaf(m[1], vp,  m[3]));
    float n10 = fmaf(m[4], vx,  fmaf(m[5], cxp, m[6]));
    float n11 = fmaf(m[4], cxp, fmaf(m[5], vp,  m[7]));
    float d00 = fmaf(m[8],  vx,  fmaf(m[9],  cxp, m[10]));
    float d01 = fmaf(m[8],  cxp, fmaf(m[9],  vp,  m[11]));
    float d10 = fmaf(m[12], vx,  fmaf(m[13], cxp, m[14]));
    float d11 = fmaf(m[12], cxp, fmaf(m[13], vp,  m[15]));
    float rdet = 1.0f / fmaf(d00, d11, -d01*d10);
    float p00 = fmaf(n00, d11, -n01*d10) * rdet;
    float p01 = fmaf(n01, d00, -n00*d01) * rdet;
    float p10 = fmaf(n10, d11, -n11*d10) * rdet;
    float p11 = fmaf(n11, d00, -n10*d01) * rdet;
    vx = p00; vp = p11; cxp = 0.5f*(p01 + p10);
}

// XCD-aware bijective swizzle (n % 8 == 0).
__device__ __forceinline__ int xcd_swz(int bx, int n)
{
    return (bx & 7) * (n >> 3) + (bx >> 3);
}

} // namespace gk

// ------------------------------------------------------------- fused kernel
__global__ void __launch_bounds__(256, 6)
kfused(const float* __restrict__ dy, const float* __restrict__ state,
       const float* __restrict__ fin, const float* __restrict__ kp,
       M16 ml, M16 mh, float* __restrict__ out)
{
    using namespace gk;
    __shared__ float tsh[2][8];                  // wave0 total map per batch
    const int lane = threadIdx.x & 63;           // segment within wave
    const int wv   = threadIdx.x >> 6;
    const int bi   = wv >> 1;                    // batch within block (0/1)
    const int w    = wv & 1;                     // wave half (0/1)
    const int g    = xcd_swz(blockIdx.x, gridDim.x);   // 2048 blocks
    const int b    = g*2 + bi;                   // wave-uniform batch

    // Wave-uniform small loads (scalarized).
    const float k00 = kp[0], k01 = kp[1], k10 = kp[2], k11 = kp[3];
    const float x0i = state[b*6+0], x1i = state[b*6+1];
    const float vx0 = state[b*6+2], vp0 = state[b*6+3], cx0 = state[b*6+4];
    const float t0v = state[b*6+5];
    const float f0i = fin[b*2+0],   f1i = fin[b*2+1];

    // ---- Checkpoint at segment start (t = 16*(64w + lane)).
    // cov: lft(ML^lane * (w ? MH : I));  matrices are powers of one base
    // so products commute.
    float vx = vx0, vp = vp0, cxp = cx0;
    {
        float acc[16] = {1,0,0,0, 0,1,0,0, 0,0,1,0, 0,0,0,1};
        float bas[16];
        #pragma unroll
        for (int i = 0; i < 16; ++i) bas[i] = ml.m[i];
        #pragma unroll
        for (int it = 0; it < 6; ++it) {
            float t[16];
            if ((lane >> it) & 1) {
                mat4_mul(acc, bas, t);
                #pragma unroll
                for (int i = 0; i < 16; ++i) acc[i] = t[i];
            }
            if (it < 5) {
                mat4_mul(bas, bas, t);
                #pragma unroll
                for (int i = 0; i < 16; ++i) bas[i] = t[i];
            }
        }
        if (w) {                                  // wave-uniform
            float t[16];
            mat4_mul(acc, mh.m, t);
            #pragma unroll
            for (int i = 0; i < 16; ++i) acc[i] = t[i];
        }
        lft_apply(acc, vx, vp, cxp);
    }
    // f: Mf16 = (I+dtK)^16; a = Mf16^lane; if w: a *= Mf16^64.
    float f0 = f0i, f1 = f1i;
    {
        float m00 = fmaf(DT,k00,1.f), m01 = DT*k01;
        float m10 = DT*k10,           m11 = fmaf(DT,k11,1.f);
        #pragma unroll
        for (int i = 0; i < 4; ++i) {
            float a = fmaf(m00,m00, m01*m10);
            float q = fmaf(m00,m01, m01*m11);
            float c = fmaf(m10,m00, m11*m10);
            float d = fmaf(m10,m01, m11*m11);
            m00=a; m01=q; m10=c; m11=d;
        }
        float a00=1.f, a01=0.f, a10=0.f, a11=1.f;
        #pragma unroll
        for (int it = 0; it < 6; ++it) {
            if ((lane >> it) & 1) {
                float x0 = fmaf(a00,m00, a01*m10);
                float x1 = fmaf(a00,m01, a01*m11);
                float x2 = fmaf(a10,m00, a11*m10);
                float x3 = fmaf(a10,m01, a11*m11);
                a00=x0; a01=x1; a10=x2; a11=x3;
            }
            // after loop m = Mf16^32
            float x0 = fmaf(m00,m00, m01*m10);
            float x1 = fmaf(m00,m01, m01*m11);
            float x2 = fmaf(m10,m00, m11*m10);
            float x3 = fmaf(m10,m01, m11*m11);
            m00=x0; m01=x1; m10=x2; m11=x3;
        }
        if (w) {                                  // m is now Mf16^64
            float x0 = fmaf(a00,m00, a01*m10);
            float x1 = fmaf(a00,m01, a01*m11);
            float x2 = fmaf(a10,m00, a11*m10);
            float x3 = fmaf(a10,m01, a11*m11);
            a00=x0; a01=x1; a10=x2; a11=x3;
        }
        float nf0 = fmaf(a00, f0, a01*f1);
        float nf1 = fmaf(a10, f0, a11*f1);
        f0 = nf0; f1 = nf1;
    }
    const float vxs = vx, vps = vp, cxs = cxp, f0s = f0, f1s = f1;

    // ---- Load lane's 128B dy slice (wave covers contiguous 8KB half-row).
    const float4* base = reinterpret_cast<const float4*>(dy)
                       + (size_t)b*ROWF4 + w*512 + lane*8;
    float4 v[8];
    #pragma unroll
    for (int j = 0; j < 8; ++j) v[j] = base[j];

    // ---- Phase 1: per-segment affine map x_end = X x_start + Q (16 steps).
    float X00 = 1.f, X01 = 0.f, X10 = 0.f, X11 = 1.f, Q0 = 0.f, Q1 = 0.f;
    #pragma unroll
    for (int j = 0; j < 8; ++j) {
        #pragma unroll
        for (int h = 0; h < 2; ++h) {
            float dy0 = h ? v[j].z : v[j].x;
            float xi0, xi1, nf0;
            covf_step(vx, vp, cxp, f0, f1, k00, k01, k10, k11, xi0, xi1, nf0);
            float p00 = fmaf(-DTC, xi0, P00c);
            float p10 = fmaf(-DTC, xi1, P10c);
            float r0  = xi0*dy0;
            float r1  = fmaf(DT, nf0, xi1*dy0);
            float nX00 = fmaf(p00, X00, P01c*X10);
            float nX01 = fmaf(p00, X01, P01c*X11);
            float nX10 = fmaf(p10, X00, P11c*X10);
            float nX11 = fmaf(p10, X01, P11c*X11);
            float nQ0  = fmaf(p00, Q0, fmaf(P01c, Q1, r0));
            float nQ1  = fmaf(p10, Q0, fmaf(P11c, Q1, r1));
            X00 = nX00; X01 = nX01; X10 = nX10; X11 = nX11; Q0 = nQ0; Q1 = nQ1;
        }
    }

    // ---- Wave-local inclusive scan of affine maps (apply recv first).
    float A00 = X00, A01 = X01, A10 = X10, A11 = X11, B0 = Q0, B1 = Q1;
    #pragma unroll
    for (int d = 1; d < 64; d <<= 1) {
        float r00 = __shfl_up(A00, d);
        float r01 = __shfl_up(A01, d);
        float r10 = __shfl_up(A10, d);
        float r11 = __shfl_up(A11, d);
        float rB0 = __shfl_up(B0,  d);
        float rB1 = __shfl_up(B1,  d);
        if (lane >= d) {
            float n00 = fmaf(A00, r00, A01*r10);
            float n01 = fmaf(A00, r01, A01*r11);
            float n10 = fmaf(A10, r00, A11*r10);
            float n11 = fmaf(A10, r01, A11*r11);
            float nB0 = fmaf(A00, rB0, fmaf(A01, rB1, B0));
            float nB1 = fmaf(A10, rB0, fmaf(A11, rB1, B1));
            A00=n00; A01=n01; A10=n10; A11=n11; B0=nB0; B1=nB1;
        }
    }

    // ---- Cross-wave stitch: wave0 total map -> wave1 via LDS.
    if (w == 0 && lane == 63) {
        tsh[bi][0]=A00; tsh[bi][1]=A01; tsh[bi][2]=A10;
        tsh[bi][3]=A11; tsh[bi][4]=B0;  tsh[bi][5]=B1;
    }
    __syncthreads();
    float xb0 = x0i, xb1 = x1i;
    if (w == 1) {
        float T00=tsh[bi][0], T01=tsh[bi][1], T10=tsh[bi][2];
        float T11=tsh[bi][3], TB0=tsh[bi][4], TB1=tsh[bi][5];
        xb0 = fmaf(T00, x0i, fmaf(T01, x1i, TB0));
        xb1 = fmaf(T10, x0i, fmaf(T11, x1i, TB1));
    }

    // Exclusive prefix -> x at this segment's start.
    float e00 = __shfl_up(A00, 1);
    float e01 = __shfl_up(A01, 1);
    float e10 = __shfl_up(A10, 1);
    float e11 = __shfl_up(A11, 1);
    float eB0 = __shfl_up(B0,  1);
    float eB1 = __shfl_up(B1,  1);
    float x0 = (lane == 0) ? xb0 : fmaf(e00, xb0, fmaf(e01, xb1, eB0));
    float x1 = (lane == 0) ? xb1 : fmaf(e10, xb0, fmaf(e11, xb1, eB1));

    // ---- Phase 2: replay from checkpoint, emit dy_hat into v[].
    vx = vxs; vp = vps; cxp = cxs; f0 = f0s; f1 = f1s;
    #pragma unroll
    for (int j = 0; j < 8; ++j) {
        float yh0, yh1;
        #pragma unroll
        for (int h = 0; h < 2; ++h) {
            float dy0 = h ? v[j].z : v[j].x;
            float yh  = YC * x0;              // dy_hat uses pre-update x
            if (h) yh1 = yh; else yh0 = yh;
            float xi0, xi1, nf0;
            covf_step(vx, vp, cxp, f0, f1, k00, k01, k10, k11, xi0, xi1, nf0);
            float p00 = fmaf(-DTC, xi0, P00c);
            float p10 = fmaf(-DTC, xi1, P10c);
            float r0  = xi0*dy0;
            float r1  = fmaf(DT, nf0, xi1*dy0);
            float nx0 = fmaf(p00, x0, fmaf(P01c, x1, r0));
            float nx1 = fmaf(p10, x0, fmaf(P11c, x1, r1));
            x0 = nx0; x1 = nx1;
        }
        v[j] = make_float4(yh0, 0.f, yh1, 0.f);
    }

    // Store lane's 128B dy_hat slice.
    float4* dst = reinterpret_cast<float4*>(out + 6*NBATCH)
                + (size_t)b*ROWF4 + w*512 + lane*8;
    #pragma unroll
    for (int j = 0; j < 8; ++j) dst[j] = v[j];

    // Segment 127 (wave 1, lane 63) holds t=2048 state.
    if (w == 1 && lane == 63) {
        out[b*6+0] = x0; out[b*6+1] = x1;
        out[b*6+2] = vx; out[b*6+3] = vp; out[b*6+4] = cxp;
        out[b*6+5] = t0v + 2.048f;
        float* fo = out + 6*NBATCH + (size_t)NBATCH*NT*2;
        fo[b*2+0] = f0; fo[b*2+1] = f1;
    }
}

// Host: LFT step matrix (Kalman form) ^ (2^log2n), computed in double.
static M16 build_m_pow(int log2n)
{
    const double dt = 0.001;
    const double a00 = -0.15, a01 = 6.283185, a10 = -6.283185, a11 = -0.15;
    const double qq = dt * 4.0 * 0.8 * 0.9;
    const double qd = dt * 5.25;
    const double h00 = 1.0 + dt*a00, h01 = dt*a01;
    const double h10 = dt*a10,       h11 = 1.0 + dt*a11;
    const double det = h00*h11 - h01*h10;
    const double t00 = h11/det, t01 = -h10/det, t10 = -h01/det, t11 = h00/det;
    const double g00 = t00*qq, g10 = t10*qq;
    double M[4][4] = {
        { h00 + qd*g00, h01, qd*t00, qd*t01 },
        { h10 + qd*g10, h11, qd*t10, qd*t11 },
        { g00,          0.0, t00,    t01    },
        { g10,          0.0, t10,    t11    },
    };
    for (int it = 0; it < log2n; ++it) {
        double R[4][4];
        for (int i = 0; i < 4; ++i)
            for (int j = 0; j < 4; ++j) {
                double acc = 0.0;
                for (int k = 0; k < 4; ++k) acc += M[i][k]*M[k][j];
                R[i][j] = acc;
            }
        for (int i = 0; i < 4; ++i)
            for (int j = 0; j < 4; ++j) M[i][j] = R[i][j];
    }
    M16 r;
    for (int i = 0; i < 4; ++i)
        for (int j = 0; j < 4; ++j) r.m[i*4+j] = (float)M[i][j];
    return r;
}

extern "C" void kernel_launch(void* const* d_in, const int* in_sizes, int n_in,
                              void* d_out, int out_size, void* d_ws, size_t ws_size,
                              hipStream_t stream)
{
    const float* dy    = (const float*)d_in[0];
    const float* state = (const float*)d_in[1];
    const float* fin   = (const float*)d_in[2];
    const float* kp    = (const float*)d_in[3];
    float* out = (float*)d_out;

    M16 ml = build_m_pow(4);    // M_step^16
    M16 mh = build_m_pow(10);   // M_step^1024

    kfused<<<dim3(NBATCH/2), dim3(256), 0, stream>>>(dy, state, fin, kp, ml, mh, out);
}

// Round 13
// 50.046 us; speedup vs baseline: 1.3458x; 1.3458x over previous
//
#include <hip/hip_runtime.h>
#include <cmath>

// GRNN_3547642986522 — B=4096 filters, T=2048 steps. R13.
// Math: cov (Riccati) evolves by a CONSTANT LFT per Euler step (== Kalman LFT
// step to O(dt^2)); ML = M_step^16 computed on host in double. x affine given
// cov; f linear; t closed-form.
// kinit (1 block, 128 thr): thread e computes ML^e (float binary matpow) and
//   Mf16^e (2x2) -> 10KB table in ws. Batch-independent, computed ONCE.
// kfused: 2 waves per batch, lane = segment (128 segs x 16 steps). Lane loads
//   its 20-float checkpoint transform from the table (L2-hot) -> no matpow in
//   the hot kernel, VGPR peak ~60 (fits launch_bounds(256,4), no spill).
//   Phase 1: per-segment affine map (X,Q); wave shfl_up scan; wave0 total map
//   -> wave1 via LDS stitch. Phase 2: replay 16 steps, emit dy_hat.
// Memory: wave = contiguous 8KB half-row loads+stores, block = 2 batches,
// XCD-swizzled. 8192 waves = 32/CU capacity.

#define NBATCH 4096
#define NT     2048
#define ROWF4  1024        // float4 per dy row

struct M16 { float m[16]; };

namespace gk {

constexpr float DT   = 0.001f;
constexpr float A00  = -0.15f;
constexpr float A01  = 6.283185f;
constexpr float A10  = -6.283185f;
constexpr float A11  = -0.15f;
constexpr float C0   = 1.6970562748477141f;
constexpr float DD   = 5.25f;

constexpr float P00c = 1.0f + DT*A00;
constexpr float P01c = DT*A01;
constexpr float P10c = DT*A10;
constexpr float P11c = 1.0f + DT*A11;
constexpr float DTC  = DT*C0;
constexpr float QQ   = DT*C0*C0;
constexpr float cVA  = 1.0f + 2.0f*DT*A00;
constexpr float cVB  = 2.0f*DT*A01;
constexpr float cVBn = 2.0f*DT*A10;
constexpr float cVD  = DT*DD;
constexpr float cCA  = 1.0f + DT*(A00+A11);
constexpr float cCB  = DT*A10;
constexpr float cCC  = DT*A01;
constexpr float YC   = C0*DT;

__device__ __forceinline__ void cov_step(float& vx, float& vp, float& cxp)
{
    float a1 = fmaf(-QQ, vx,  cVA);
    float b1 = fmaf(cVB, cxp, cVD);
    float a2 = fmaf(-QQ, cxp, cVBn);
    float b2 = fmaf(a2,  cxp, cVD);
    float a3 = fmaf(-QQ, vx,  cCA);
    float m  = cCC * vp;
    float c3 = fmaf(cCB, vx,  m);
    float nvx = fmaf(a1,  vx,  b1);
    float nvp = fmaf(cVA, vp,  b2);
    float ncx = fmaf(a3,  cxp, c3);
    vx = nvx; vp = nvp; cxp = ncx;
}

__device__ __forceinline__ void covf_step(
    float& vx, float& vp, float& cxp, float& f0, float& f1,
    float k00, float k01, float k10, float k11,
    float& xi0o, float& xi1o, float& nf0o)
{
    float xi0 = C0*vx, xi1 = C0*cxp;
    float nf0 = fmaf(DT, fmaf(k00, f0, k01*f1), f0);
    float nf1 = fmaf(DT, fmaf(k10, f0, k11*f1), f1);
    xi0o = xi0; xi1o = xi1; nf0o = nf0;
    cov_step(vx, vp, cxp);
    f0 = nf0; f1 = nf1;
}

__device__ __forceinline__ void mat4_mul(const float* A, const float* B, float* C)
{
    #pragma unroll
    for (int i = 0; i < 4; ++i)
        #pragma unroll
        for (int j = 0; j < 4; ++j) {
            float acc = A[i*4+0] * B[0*4+j];
            acc = fmaf(A[i*4+1], B[1*4+j], acc);
            acc = fmaf(A[i*4+2], B[2*4+j], acc);
            acc = fmaf(A[i*4+3], B[3*4+j], acc);
            C[i*4+j] = acc;
        }
}

// P -> (E P + F)(G P + H)^-1, P = [[vx,cxp],[cxp,vp]].
__device__ __forceinline__ void lft_apply(const float* m, float& vx, float& vp, float& cxp)
{
    float n00 = fmaf(m[0], vx,  fmaf(m[1], cxp, m[2]));
    float n01 = fmaf(m[0], cxp, fmaf(m[1], vp,  m[3]));
    float n10 = fmaf(m[4], vx,  fmaf(m[5], cxp, m[6]));
    float n11 = fmaf(m[4], cxp, fmaf(m[5], vp,  m[7]));
    float d00 = fmaf(m[8],  vx,  fmaf(m[9],  cxp, m[10]));
    float d01 = fmaf(m[8],  cxp, fmaf(m[9],  vp,  m[11]));
    float d10 = fmaf(m[12], vx,  fmaf(m[13], cxp, m[14]));
    float d11 = fmaf(m[12], cxp, fmaf(m[13], vp,  m[15]));
    float rdet = 1.0f / fmaf(d00, d11, -d01*d10);
    float p00 = fmaf(n00, d11, -n01*d10) * rdet;
    float p01 = fmaf(n01, d00, -n00*d01) * rdet;
    float p10 = fmaf(n10, d11, -n11*d10) * rdet;
    float p11 = fmaf(n11, d00, -n10*d01) * rdet;
    vx = p00; vp = p11; cxp = 0.5f*(p01 + p10);
}

// XCD-aware bijective swizzle (n % 8 == 0).
__device__ __forceinline__ int xcd_swz(int bx, int n)
{
    return (bx & 7) * (n >> 3) + (bx >> 3);
}

} // namespace gk

// ---------------------------------------------------------------- kinit
// Thread e (0..127): ws[e*16..] = ML^e; ws[2048 + e*4..] = Mf16^e.
__global__ void __launch_bounds__(128, 1)
kinit(const float* __restrict__ kp, M16 mlb, float* __restrict__ ws)
{
    using namespace gk;
    const int e = threadIdx.x;

    float acc[16] = {1,0,0,0, 0,1,0,0, 0,0,1,0, 0,0,0,1};
    float bas[16];
    #pragma unroll
    for (int i = 0; i < 16; ++i) bas[i] = mlb.m[i];
    #pragma unroll
    for (int it = 0; it < 7; ++it) {
        float t[16];
        if ((e >> it) & 1) {
            mat4_mul(acc, bas, t);
            #pragma unroll
            for (int i = 0; i < 16; ++i) acc[i] = t[i];
        }
        if (it < 6) {
            mat4_mul(bas, bas, t);
            #pragma unroll
            for (int i = 0; i < 16; ++i) bas[i] = t[i];
        }
    }
    #pragma unroll
    for (int i = 0; i < 16; ++i) ws[e*16 + i] = acc[i];

    // Mf16 = (I + dt K)^16, then ^e.
    float m00 = fmaf(DT,kp[0],1.f), m01 = DT*kp[1];
    float m10 = DT*kp[2],           m11 = fmaf(DT,kp[3],1.f);
    #pragma unroll
    for (int i = 0; i < 4; ++i) {
        float a = fmaf(m00,m00, m01*m10);
        float q = fmaf(m00,m01, m01*m11);
        float c = fmaf(m10,m00, m11*m10);
        float d = fmaf(m10,m01, m11*m11);
        m00=a; m01=q; m10=c; m11=d;
    }
    float a00=1.f, a01=0.f, a10=0.f, a11=1.f;
    #pragma unroll
    for (int it = 0; it < 7; ++it) {
        if ((e >> it) & 1) {
            float x0 = fmaf(a00,m00, a01*m10);
            float x1 = fmaf(a00,m01, a01*m11);
            float x2 = fmaf(a10,m00, a11*m10);
            float x3 = fmaf(a10,m01, a11*m11);
            a00=x0; a01=x1; a10=x2; a11=x3;
        }
        if (it < 6) {
            float x0 = fmaf(m00,m00, m01*m10);
            float x1 = fmaf(m00,m01, m01*m11);
            float x2 = fmaf(m10,m00, m11*m10);
            float x3 = fmaf(m10,m01, m11*m11);
            m00=x0; m01=x1; m10=x2; m11=x3;
        }
    }
    ws[2048 + e*4 + 0] = a00;  ws[2048 + e*4 + 1] = a01;
    ws[2048 + e*4 + 2] = a10;  ws[2048 + e*4 + 3] = a11;
}

// ------------------------------------------------------------- fused kernel
__global__ void __launch_bounds__(256, 4)
kfused(const float* __restrict__ dy, const float* __restrict__ state,
       const float* __restrict__ fin, const float* __restrict__ kp,
       const float* __restrict__ ws, float* __restrict__ out)
{
    using namespace gk;
    __shared__ float tsh[2][8];                  // wave0 total map per batch
    const int lane = threadIdx.x & 63;           // segment within wave
    const int wv   = threadIdx.x >> 6;
    const int bi   = wv >> 1;                    // batch within block (0/1)
    const int w    = wv & 1;                     // wave half (0/1)
    const int g    = xcd_swz(blockIdx.x, gridDim.x);   // 2048 blocks
    const int b    = g*2 + bi;                   // wave-uniform batch
    const int e    = (w << 6) | lane;            // global segment 0..127

    // Wave-uniform small loads.
    const float k00 = kp[0], k01 = kp[1], k10 = kp[2], k11 = kp[3];
    const float x0i = state[b*6+0], x1i = state[b*6+1];
    const float vx0 = state[b*6+2], vp0 = state[b*6+3], cx0 = state[b*6+4];
    const float t0v = state[b*6+5];
    const float f0i = fin[b*2+0],   f1i = fin[b*2+1];

    // ---- Checkpoint at segment start via table (20 floats, L2-hot).
    float vx = vx0, vp = vp0, cxp = cx0;
    {
        const float4* tml = reinterpret_cast<const float4*>(ws) + e*4;
        float4 q0 = tml[0], q1 = tml[1], q2 = tml[2], q3 = tml[3];
        float m[16] = { q0.x,q0.y,q0.z,q0.w, q1.x,q1.y,q1.z,q1.w,
                        q2.x,q2.y,q2.z,q2.w, q3.x,q3.y,q3.z,q3.w };
        lft_apply(m, vx, vp, cxp);
    }
    float4 fm = reinterpret_cast<const float4*>(ws + 2048)[e];
    float f0 = fmaf(fm.x, f0i, fm.y*f1i);
    float f1 = fmaf(fm.z, f0i, fm.w*f1i);
    const float vxs = vx, vps = vp, cxs = cxp, f0s = f0, f1s = f1;

    // ---- Load lane's 128B dy slice (wave covers contiguous 8KB half-row).
    const float4* base = reinterpret_cast<const float4*>(dy)
                       + (size_t)b*ROWF4 + w*512 + lane*8;
    float4 v[8];
    #pragma unroll
    for (int j = 0; j < 8; ++j) v[j] = base[j];

    // ---- Phase 1: per-segment affine map x_end = X x_start + Q (16 steps).
    float X00 = 1.f, X01 = 0.f, X10 = 0.f, X11 = 1.f, Q0 = 0.f, Q1 = 0.f;
    #pragma unroll
    for (int j = 0; j < 8; ++j) {
        #pragma unroll
        for (int h = 0; h < 2; ++h) {
            float dy0 = h ? v[j].z : v[j].x;
            float xi0, xi1, nf0;
            covf_step(vx, vp, cxp, f0, f1, k00, k01, k10, k11, xi0, xi1, nf0);
            float p00 = fmaf(-DTC, xi0, P00c);
            float p10 = fmaf(-DTC, xi1, P10c);
            float r0  = xi0*dy0;
            float r1  = fmaf(DT, nf0, xi1*dy0);
            float nX00 = fmaf(p00, X00, P01c*X10);
            float nX01 = fmaf(p00, X01, P01c*X11);
            float nX10 = fmaf(p10, X00, P11c*X10);
            float nX11 = fmaf(p10, X01, P11c*X11);
            float nQ0  = fmaf(p00, Q0, fmaf(P01c, Q1, r0));
            float nQ1  = fmaf(p10, Q0, fmaf(P11c, Q1, r1));
            X00 = nX00; X01 = nX01; X10 = nX10; X11 = nX11; Q0 = nQ0; Q1 = nQ1;
        }
    }

    // ---- Wave-local inclusive scan of affine maps (apply recv first).
    float A00 = X00, A01 = X01, A10 = X10, A11 = X11, B0 = Q0, B1 = Q1;
    #pragma unroll
    for (int d = 1; d < 64; d <<= 1) {
        float r00 = __shfl_up(A00, d);
        float r01 = __shfl_up(A01, d);
        float r10 = __shfl_up(A10, d);
        float r11 = __shfl_up(A11, d);
        float rB0 = __shfl_up(B0,  d);
        float rB1 = __shfl_up(B1,  d);
        if (lane >= d) {
            float n00 = fmaf(A00, r00, A01*r10);
            float n01 = fmaf(A00, r01, A01*r11);
            float n10 = fmaf(A10, r00, A11*r10);
            float n11 = fmaf(A10, r01, A11*r11);
            float nB0 = fmaf(A00, rB0, fmaf(A01, rB1, B0));
            float nB1 = fmaf(A10, rB0, fmaf(A11, rB1, B1));
            A00=n00; A01=n01; A10=n10; A11=n11; B0=nB0; B1=nB1;
        }
    }

    // ---- Cross-wave stitch: wave0 total map -> wave1 via LDS.
    if (w == 0 && lane == 63) {
        tsh[bi][0]=A00; tsh[bi][1]=A01; tsh[bi][2]=A10;
        tsh[bi][3]=A11; tsh[bi][4]=B0;  tsh[bi][5]=B1;
    }
    __syncthreads();
    float xb0 = x0i, xb1 = x1i;
    if (w == 1) {
        float T00=tsh[bi][0], T01=tsh[bi][1], T10=tsh[bi][2];
        float T11=tsh[bi][3], TB0=tsh[bi][4], TB1=tsh[bi][5];
        xb0 = fmaf(T00, x0i, fmaf(T01, x1i, TB0));
        xb1 = fmaf(T10, x0i, fmaf(T11, x1i, TB1));
    }

    // Exclusive prefix -> x at this segment's start.
    float e00 = __shfl_up(A00, 1);
    float e01 = __shfl_up(A01, 1);
    float e10 = __shfl_up(A10, 1);
    float e11 = __shfl_up(A11, 1);
    float eB0 = __shfl_up(B0,  1);
    float eB1 = __shfl_up(B1,  1);
    float x0 = (lane == 0) ? xb0 : fmaf(e00, xb0, fmaf(e01, xb1, eB0));
    float x1 = (lane == 0) ? xb1 : fmaf(e10, xb0, fmaf(e11, xb1, eB1));

    // ---- Phase 2: replay from checkpoint, emit dy_hat into v[].
    vx = vxs; vp = vps; cxp = cxs; f0 = f0s; f1 = f1s;
    #pragma unroll
    for (int j = 0; j < 8; ++j) {
        float yh0, yh1;
        #pragma unroll
        for (int h = 0; h < 2; ++h) {
            float dy0 = h ? v[j].z : v[j].x;
            float yh  = YC * x0;              // dy_hat uses pre-update x
            if (h) yh1 = yh; else yh0 = yh;
            float xi0, xi1, nf0;
            covf_step(vx, vp, cxp, f0, f1, k00, k01, k10, k11, xi0, xi1, nf0);
            float p00 = fmaf(-DTC, xi0, P00c);
            float p10 = fmaf(-DTC, xi1, P10c);
            float r0  = xi0*dy0;
            float r1  = fmaf(DT, nf0, xi1*dy0);
            float nx0 = fmaf(p00, x0, fmaf(P01c, x1, r0));
            float nx1 = fmaf(p10, x0, fmaf(P11c, x1, r1));
            x0 = nx0; x1 = nx1;
        }
        v[j] = make_float4(yh0, 0.f, yh1, 0.f);
    }

    // Store lane's 128B dy_hat slice.
    float4* dst = reinterpret_cast<float4*>(out + 6*NBATCH)
                + (size_t)b*ROWF4 + w*512 + lane*8;
    #pragma unroll
    for (int j = 0; j < 8; ++j) dst[j] = v[j];

    // Segment 127 (wave 1, lane 63) holds t=2048 state.
    if (w == 1 && lane == 63) {
        out[b*6+0] = x0; out[b*6+1] = x1;
        out[b*6+2] = vx; out[b*6+3] = vp; out[b*6+4] = cxp;
        out[b*6+5] = t0v + 2.048f;
        float* fo = out + 6*NBATCH + (size_t)NBATCH*NT*2;
        fo[b*2+0] = f0; fo[b*2+1] = f1;
    }
}

// Host: LFT step matrix (Kalman form) ^ 16, computed in double.
static M16 build_m_pow(int log2n)
{
    const double dt = 0.001;
    const double a00 = -0.15, a01 = 6.283185, a10 = -6.283185, a11 = -0.15;
    const double qq = dt * 4.0 * 0.8 * 0.9;
    const double qd = dt * 5.25;
    const double h00 = 1.0 + dt*a00, h01 = dt*a01;
    const double h10 = dt*a10,       h11 = 1.0 + dt*a11;
    const double det = h00*h11 - h01*h10;
    const double t00 = h11/det, t01 = -h10/det, t10 = -h01/det, t11 = h00/det;
    const double g00 = t00*qq, g10 = t10*qq;
    double M[4][4] = {
        { h00 + qd*g00, h01, qd*t00, qd*t01 },
        { h10 + qd*g10, h11, qd*t10, qd*t11 },
        { g00,          0.0, t00,    t01    },
        { g10,          0.0, t10,    t11    },
    };
    for (int it = 0; it < log2n; ++it) {
        double R[4][4];
        for (int i = 0; i < 4; ++i)
            for (int j = 0; j < 4; ++j) {
                double acc = 0.0;
                for (int k = 0; k < 4; ++k) acc += M[i][k]*M[k][j];
                R[i][j] = acc;
            }
        for (int i = 0; i < 4; ++i)
            for (int j = 0; j < 4; ++j) M[i][j] = R[i][j];
    }
    M16 r;
    for (int i = 0; i < 4; ++i)
        for (int j = 0; j < 4; ++j) r.m[i*4+j] = (float)M[i][j];
    return r;
}

extern "C" void kernel_launch(void* const* d_in, const int* in_sizes, int n_in,
                              void* d_out, int out_size, void* d_ws, size_t ws_size,
                              hipStream_t stream)
{
    const float* dy    = (const float*)d_in[0];
    const float* state = (const float*)d_in[1];
    const float* fin   = (const float*)d_in[2];
    const float* kp    = (const float*)d_in[3];
    float* out = (float*)d_out;
    float* ws  = (float*)d_ws;   // 10 KB table

    M16 mlb = build_m_pow(4);    // M_step^16

    kinit<<<dim3(1), dim3(128), 0, stream>>>(kp, mlb, ws);
    kfused<<<dim3(NBATCH/2), dim3(256), 0, stream>>>(dy, state, fin, kp, ws, out);
}